// Round 10
// baseline (715.756 us; speedup 1.0000x reference)
//
#include <hip/hip_runtime.h>
#include <hip/hip_bf16.h>
#include <stdint.h>

#define NB 512
#define NL 128
#define ND 512

typedef __bf16 bf16;
typedef __bf16 bf16x8 __attribute__((ext_vector_type(8)));
typedef float  f32x4  __attribute__((ext_vector_type(4)));

// ------- K1: gather embed rows -> bf16 + partial sumsq; y==2: att^T ------
// grid (NB, 3, 8), 256 thr. Dedicated high-occupancy BW kernel (~68us).
// Table reads nontemporal so they don't evict Ab/Bb from L3.
__global__ __launch_bounds__(256) void k_gather(const int* __restrict__ ctx1,
                                                const int* __restrict__ ctx2,
                                                const float* __restrict__ table,
                                                bf16* __restrict__ d1,
                                                bf16* __restrict__ d2,
                                                float* __restrict__ ss,
                                                const float* __restrict__ att,
                                                bf16* __restrict__ attT) {
    const int b = blockIdx.x, side = blockIdx.y, zc = blockIdx.z, t = threadIdx.x;
    if (side == 2) {                      // att transpose slice
        int chunk = b * 8 + zc;
        if (chunk < 1024) {
            int i = chunk * 256 + t;      // over 512*512
            int n = i >> 9, k = i & 511;
            attT[i] = (bf16)att[k * 512 + n];
        }
        return;
    }
    const int* __restrict__ ctx = side ? ctx2 : ctx1;
    bf16* __restrict__ dst = side ? d2 : d1;
    const int base = b * NL;
    const int dv = t & 127, lr = t >> 7;
    int idxs[8];
    #pragma unroll
    for (int i = 0; i < 8; ++i) idxs[i] = ctx[base + zc * 16 + i * 2 + lr];
    float acc = 0.f;
    #pragma unroll
    for (int i = 0; i < 8; ++i) {
        int l = zc * 16 + i * 2 + lr;
        f32x4 v = __builtin_nontemporal_load(
            (const f32x4*)table + (size_t)idxs[i] * (ND / 4) + dv);
        acc += v[0]*v[0] + v[1]*v[1] + v[2]*v[2] + v[3]*v[3];
        union { bf16 h[4]; uint2 u; } pk;
        pk.h[0] = (bf16)v[0]; pk.h[1] = (bf16)v[1];
        pk.h[2] = (bf16)v[2]; pk.h[3] = (bf16)v[3];
        *((uint2*)(dst + (size_t)(base + l) * ND) + dv) = pk.u;
    }
    for (int o = 32; o; o >>= 1) acc += __shfl_xor(acc, o);
    __shared__ float red[4];
    if ((t & 63) == 0) red[t >> 6] = acc;
    __syncthreads();
    if (t == 0) atomicAdd(&ss[side * NB + b], red[0] + red[1] + red[2] + red[3]);
}

// ---- MEGA4: m-halved T (64KB LDS), ALL operands direct global->register.
//  Single-touch A; B touched 2x (2nd L2/L3-adjacent). NO staging LDS, NO
//  barriers inside K-loops (~11 total). 68KB LDS -> 2 blk/CU, all 512
//  blocks resident in ONE round; 16 waves/CU hide L2 latency.
//  per half h (rows h*64..h*64+63):
//   ph1: acc1[4m][4n] += A-frag x attT-frag direct (wave n-range 64)
//   T-write: acc1 -> swizzled Tls[16t][64m][32] (own data, no pre-barrier)
//   ph2: accS[4m] += T-frag(LDS) x B-frag direct (wave owns 16 S-cols)
//   tanh/S-store/row-col partial sums
//  then softmax + weighted-sum epilogue (direct Ab/Bb re-read, L3-odds).
__global__ __launch_bounds__(512, 4) void k_mega4(
        const bf16* __restrict__ Ab, const bf16* __restrict__ attT,
        const bf16* __restrict__ Bb, float* __restrict__ Sout,
        const float* __restrict__ ss, const float* __restrict__ w_pred,
        const float* __restrict__ b_pred, float* __restrict__ logits) {
    const int b = blockIdx.x, row0 = b * NL, tid = threadIdx.x;
    const int lane = tid & 63, w = tid >> 6;
    const int lm = lane & 15, quad = lane >> 4;
    const int nb1 = w * 64;               // ph1 wave n-base (of 512)
    const int nb2 = w * 16;               // ph2 wave S-col base (of 128)

    __shared__ __align__(16) char smem[69632];
    bf16*  Tls  = (bf16*)smem;            // [16t][64m][32] swz, 64K
    float* rowp = (float*)smem;           // [8][64] alias (post-ph2)
    float* pA   = (float*)smem;           // final [8][512]
    float* pB   = (float*)(smem + 16384); // final [8][512]
    float* rowb = (float*)(smem + 65536); // [128] persists both halves
    float* colp = (float*)(smem + 66048); // [2][128]
    float* wrow = (float*)(smem + 67072); // [128]
    float* wcol = (float*)(smem + 67584); // [128]

    const float ssA = ss[b], ssB = ss[NB + b];
    const float sc = rsqrtf(ssA * ssB);
    float* __restrict__ Sb = Sout + (size_t)b * NL * NL;

    for (int h = 0; h < 2; ++h) {
        const int m0 = h * 64;

        // ---------- ph1: T_half = A_half @ attT^T (all direct loads) ----------
        f32x4 acc1[4][4] = {};
        for (int t = 0; t < 16; ++t) {
            const int k0 = t * 32 + quad * 8;
            bf16x8 af[4], bfm[4];
            #pragma unroll
            for (int mf = 0; mf < 4; ++mf)
                af[mf] = *(const bf16x8*)(Ab + (size_t)(row0 + m0 + mf * 16 + lm) * ND + k0);
            #pragma unroll
            for (int nf = 0; nf < 4; ++nf)
                bfm[nf] = *(const bf16x8*)(attT + (size_t)(nb1 + nf * 16 + lm) * ND + k0);
            #pragma unroll
            for (int mf = 0; mf < 4; ++mf)
                #pragma unroll
                for (int nf = 0; nf < 4; ++nf)
                    acc1[mf][nf] = __builtin_amdgcn_mfma_f32_16x16x32_bf16(
                        af[mf], bfm[nf], acc1[mf][nf], 0, 0, 0);
        }

        // ---------- T-write: own fragments only (no pre-barrier needed) ------
        // Tls[t][m][pos*8+e]: t=n>>5, kq=(n>>3)&3, e=n&7, pos=kq^((m>>1)&3)
        #pragma unroll
        for (int mf = 0; mf < 4; ++mf)
        #pragma unroll
        for (int nf = 0; nf < 4; ++nf)
        #pragma unroll
        for (int p = 0; p < 4; ++p) {
            int m = mf * 16 + quad * 4 + p;   // C/D: col=lane&15, row=quad*4+reg
            int n = nb1 + nf * 16 + lm;
            int ti = n >> 5, kq = (n >> 3) & 3, e = n & 7;
            int pos = kq ^ ((m >> 1) & 3);
            Tls[ti * 2048 + m * 32 + pos * 8 + e] = (bf16)acc1[mf][nf][p];
        }
        __syncthreads();                  // T visible to all waves

        // ---------- ph2: S_half = T_half @ B^T (T from LDS, B direct) --------
        f32x4 accS[4] = {};
        for (int t = 0; t < 16; ++t) {
            bf16x8 tf[4];
            bf16x8 bf1 = *(const bf16x8*)(Bb + (size_t)(row0 + nb2 + lm) * ND + t * 32 + quad * 8);
            #pragma unroll
            for (int mf = 0; mf < 4; ++mf) {
                int R = mf * 16 + lm;
                tf[mf] = *(const bf16x8*)&Tls[t * 2048 + R * 32 + (quad ^ ((R >> 1) & 3)) * 8];
            }
            #pragma unroll
            for (int mf = 0; mf < 4; ++mf)
                accS[mf] = __builtin_amdgcn_mfma_f32_16x16x32_bf16(
                    tf[mf], bf1, accS[mf], 0, 0, 0);
        }
        __syncthreads();                  // T reads done before rowp aliases

        // ---------- tanh + S store + partial sums ----------
        #pragma unroll
        for (int mf = 0; mf < 4; ++mf)
        #pragma unroll
        for (int p = 0; p < 4; ++p) {
            float v = tanhf(accS[mf][p] * sc);
            accS[mf][p] = v;
            int m = m0 + mf * 16 + quad * 4 + p;
            __builtin_nontemporal_store(v, &Sb[m * NL + nb2 + lm]);
        }
        #pragma unroll
        for (int mf = 0; mf < 4; ++mf)
        #pragma unroll
        for (int p = 0; p < 4; ++p) {
            float r = accS[mf][p];        // this wave's 16 cols of row m
            r += __shfl_xor(r, 1); r += __shfl_xor(r, 2);
            r += __shfl_xor(r, 4); r += __shfl_xor(r, 8);
            if (lm == 0) rowp[w * 64 + mf * 16 + quad * 4 + p] = r;
        }
        {
            float cv = 0.f;
            #pragma unroll
            for (int mf = 0; mf < 4; ++mf)
                #pragma unroll
                for (int p = 0; p < 4; ++p) cv += accS[mf][p];
            cv += __shfl_xor(cv, 16); cv += __shfl_xor(cv, 32);
            if (quad == 0) colp[h * 128 + nb2 + lm] = cv;
        }
        __syncthreads();                  // rowp visible
        if (tid < 64) {
            float r = 0.f;
            #pragma unroll
            for (int i = 0; i < 8; ++i) r += rowp[i * 64 + tid];
            rowb[m0 + tid] = r;
        }
        __syncthreads();                  // rowp consumed (next half rewrites)
    }

    // ---------- softmax over means (wave0: rows, wave1: cols) ----------
    if (tid < 64) {
        float a  = rowb[tid] * (1.f / NL);
        float c2 = rowb[tid + 64] * (1.f / NL);
        float mx = fmaxf(a, c2);
        for (int o = 32; o; o >>= 1) mx = fmaxf(mx, __shfl_xor(mx, o));
        float e0 = expf(a - mx), e1 = expf(c2 - mx);
        float s = e0 + e1;
        for (int o = 32; o; o >>= 1) s += __shfl_xor(s, o);
        float inv = 1.f / s;
        wrow[tid] = e0 * inv; wrow[tid + 64] = e1 * inv;
    } else if (tid < 128) {
        int q = tid - 64;
        float a  = (colp[q] + colp[128 + q]) * (1.f / NL);
        float c2 = (colp[q + 64] + colp[192 + q]) * (1.f / NL);
        float mx = fmaxf(a, c2);
        for (int o = 32; o; o >>= 1) mx = fmaxf(mx, __shfl_xor(mx, o));
        float e0 = expf(a - mx), e1 = expf(c2 - mx);
        float s = e0 + e1;
        for (int o = 32; o; o >>= 1) s += __shfl_xor(s, o);
        float inv = 1.f / s;
        wcol[q] = e0 * inv; wcol[q + 64] = e1 * inv;
    }
    __syncthreads();

    // ---- weighted sums of A/B rows (Tls dead -> pA/pB; L3-odds reread) ----
    const int c = tid & 63, g = tid >> 6;
    const bf16* __restrict__ Abase = Ab + (size_t)b * NL * ND;
    const bf16* __restrict__ Bbase = Bb + (size_t)b * NL * ND;
    float aacc[8] = {}, bacc[8] = {};
    for (int l = g; l < NL; l += 8) {
        float wr = wrow[l], wc = wcol[l];
        bf16x8 va = *(const bf16x8*)(Abase + (size_t)l * ND + c * 8);
        bf16x8 vb = *(const bf16x8*)(Bbase + (size_t)l * ND + c * 8);
        #pragma unroll
        for (int j = 0; j < 8; ++j) {
            aacc[j] += wr * (float)va[j];
            bacc[j] += wc * (float)vb[j];
        }
    }
    #pragma unroll
    for (int j = 0; j < 8; ++j) {
        pA[g * ND + c * 8 + j] = aacc[j];
        pB[g * ND + c * 8 + j] = bacc[j];
    }
    __syncthreads();

    if (tid < 64) {
        float dot = 0.f;
        #pragma unroll
        for (int j = 0; j < 8; ++j) {
            int d = tid * 8 + j;
            float na = 0.f, nb = 0.f;
            #pragma unroll
            for (int g2 = 0; g2 < 8; ++g2) {
                na += pA[g2 * ND + d];
                nb += pB[g2 * ND + d];
            }
            dot += na * nb * w_pred[d];
        }
        for (int o = 32; o; o >>= 1) dot += __shfl_xor(dot, o);
        if (tid == 0)
            logits[b] = dot * rsqrtf(ssA) * rsqrtf(ssB) + b_pred[0];
    }
}

extern "C" void kernel_launch(void* const* d_in, const int* in_sizes, int n_in,
                              void* d_out, int out_size, void* d_ws, size_t ws_size,
                              hipStream_t stream) {
    const int*   t1c = (const int*)d_in[2];
    const int*   t2c = (const int*)d_in[3];
    const float* emb = (const float*)d_in[4];
    const float* att = (const float*)d_in[5];
    const float* wp  = (const float*)d_in[6];
    const float* bp  = (const float*)d_in[7];

    float* out    = (float*)d_out;
    float* logits = out;
    float* S      = out + NB;      // outputs: logits(512) then S(512*128*128)

    char* ws = (char*)d_ws;
    bf16*  Ab   = (bf16*)(ws);                              // 67,108,864 B
    bf16*  Bb   = (bf16*)(ws + 67108864);                   // 67,108,864 B
    bf16*  attT = (bf16*)(ws + 134217728);                  //    524,288 B
    float* ss   = (float*)(ws + 134742016);                 //      4,096 B

    hipMemsetAsync(ss, 0, 4096, stream);
    // dedicated BW kernel: gather (y=0,1) + att transpose (y=2)
    k_gather<<<dim3(NB, 3, 8), 256, 0, stream>>>(t1c, t2c, emb, Ab, Bb, ss, att, attT);
    // compute: 68KB LDS, 2 blk/CU, one resident round, barrier-free K-loops
    k_mega4<<<dim3(NB), 512, 0, stream>>>(Ab, attT, Bb, S, ss, wp, bp, logits);
}

// Round 12
// 418.589 us; speedup vs baseline: 1.7099x; 1.7099x over previous
//
#include <hip/hip_runtime.h>
#include <hip/hip_bf16.h>
#include <stdint.h>

#define NB 512
#define NL 128
#define ND 512

typedef __bf16 bf16;
typedef __bf16 bf16x8 __attribute__((ext_vector_type(8)));
typedef float  f32x4  __attribute__((ext_vector_type(4)));

#define GLDS(src, dst) __builtin_amdgcn_global_load_lds( \
    (const __attribute__((address_space(1))) void*)(src), \
    (__attribute__((address_space(3))) void*)(dst), 16, 0, 0)

// ------- K1: A-side gather -> bf16 + partial sumsq; y==1: att^T ------
// grid (NB, 2, 8), 256 thr. B-side gather moved into k_mega2b (overlapped
// with ph1 MFMA). Table reads nontemporal (single-touch, keep L3 for Ab).
__global__ __launch_bounds__(256) void k_gather(const int* __restrict__ ctx1,
                                                const float* __restrict__ table,
                                                bf16* __restrict__ d1,
                                                float* __restrict__ ss,
                                                const float* __restrict__ att,
                                                bf16* __restrict__ attT) {
    const int b = blockIdx.x, side = blockIdx.y, zc = blockIdx.z, t = threadIdx.x;
    if (side == 1) {                      // att transpose slice
        int chunk = b * 8 + zc;
        if (chunk < 1024) {
            int i = chunk * 256 + t;      // over 512*512
            int n = i >> 9, k = i & 511;
            attT[i] = (bf16)att[k * 512 + n];
        }
        return;
    }
    const int base = b * NL;
    const int dv = t & 127, lr = t >> 7;
    int idxs[8];
    #pragma unroll
    for (int i = 0; i < 8; ++i) idxs[i] = ctx1[base + zc * 16 + i * 2 + lr];
    float acc = 0.f;
    #pragma unroll
    for (int i = 0; i < 8; ++i) {
        int l = zc * 16 + i * 2 + lr;
        f32x4 v = __builtin_nontemporal_load(
            (const f32x4*)table + (size_t)idxs[i] * (ND / 4) + dv);
        acc += v[0]*v[0] + v[1]*v[1] + v[2]*v[2] + v[3]*v[3];
        union { bf16 h[4]; uint2 u; } pk;
        pk.h[0] = (bf16)v[0]; pk.h[1] = (bf16)v[1];
        pk.h[2] = (bf16)v[2]; pk.h[3] = (bf16)v[3];
        *((uint2*)(d1 + (size_t)(base + l) * ND) + dv) = pk.u;
    }
    for (int o = 32; o; o >>= 1) acc += __shfl_xor(acc, o);
    __shared__ float red[4];
    if ((t & 63) == 0) red[t >> 6] = acc;
    __syncthreads();
    if (t == 0) atomicAdd(&ss[b], red[0] + red[1] + red[2] + red[3]);
}

// ---- MEGA2b = R7's mega2 (125us) + B-gather embedded in ph1 (T14 split:
//      issue chunk t+2 after MFMA, commit chunk t at next iter top; stores
//      drained by the T-epilogue __syncthreads before ph2's first B read).
//      ssB computed block-locally. vmcnt re-counted: 8 steady / 1 at t=15.
__global__ __launch_bounds__(512) void k_mega2b(
        const bf16* __restrict__ Ab, const bf16* __restrict__ attT,
        bf16* __restrict__ Bb, const int* __restrict__ ctx2,
        const float* __restrict__ table, float* __restrict__ Sout,
        const float* __restrict__ ss, const float* __restrict__ w_pred,
        const float* __restrict__ b_pred, float* __restrict__ logits) {
    const int b = blockIdx.x, row0 = b * NL, tid = threadIdx.x;
    const int lane = tid & 63, w = tid >> 6;
    const int lm = lane & 15, quad = lane >> 4;
    const int wm  = (w & 1) * 64;             // m-half
    const int wn1 = (w >> 1) * 128;           // ph1 n-chunk (of 512)
    const int wn2 = (w >> 1) * 32;            // ph2 n-chunk (of 128)

    __shared__ __align__(16) char smem[163840];
    bf16* stA0 = (bf16*)smem;
    bf16* stA1 = (bf16*)(smem + 8192);
    bf16* stT0 = (bf16*)(smem + 16384);
    bf16* stT1 = (bf16*)(smem + 49152);
    float* redB = (float*)(smem + 81920);     // [8], free during ph1
    bf16* Tls  = (bf16*)smem;                 // 128K (post-ph1)
    bf16* sB0  = (bf16*)(smem + 131072);
    bf16* sB1  = (bf16*)(smem + 139264);
    bf16* sC0  = (bf16*)(smem + 147456);
    bf16* sC1  = (bf16*)(smem + 155648);
    float* rowb = (float*)smem;               // [4][128] (post-ph2)
    float* colb = (float*)(smem + 2048);      // [2][128]
    float* wrow = (float*)(smem + 3072);      // [128]
    float* wcol = (float*)(smem + 3584);      // [128]
    float* red2 = (float*)(smem + 4096);      // [8]

    // ---- B-gather setup: wave w owns row c*8+w of chunk c; lane covers 32B
    const int r8b = w, c8b = lane;
    int bidx[16];
    #pragma unroll
    for (int c = 0; c < 16; ++c) bidx[c] = ctx2[row0 + c * 8 + r8b];
    const float ssA = ss[b];
    float pb = 0.f;
    f32x4 bgl[2][2];                          // [chunk parity][half]

    #define BG_ISSUE(c) do {                                                  \
        const f32x4* rp_ = (const f32x4*)table + (size_t)bidx[c] * (ND/4) + c8b*2; \
        bgl[(c)&1][0] = __builtin_nontemporal_load(rp_);                      \
        bgl[(c)&1][1] = __builtin_nontemporal_load(rp_ + 1);                  \
    } while (0)
    #define BG_COMMIT(c) do {                                                 \
        f32x4 v0_ = bgl[(c)&1][0], v1_ = bgl[(c)&1][1];                       \
        pb += v0_[0]*v0_[0] + v0_[1]*v0_[1] + v0_[2]*v0_[2] + v0_[3]*v0_[3]   \
            + v1_[0]*v1_[0] + v1_[1]*v1_[1] + v1_[2]*v1_[2] + v1_[3]*v1_[3];  \
        union { bf16 h[8]; uint4 u; } pk_;                                    \
        pk_.h[0]=(bf16)v0_[0]; pk_.h[1]=(bf16)v0_[1]; pk_.h[2]=(bf16)v0_[2];  \
        pk_.h[3]=(bf16)v0_[3]; pk_.h[4]=(bf16)v1_[0]; pk_.h[5]=(bf16)v1_[1];  \
        pk_.h[6]=(bf16)v1_[2]; pk_.h[7]=(bf16)v1_[3];                         \
        *(uint4*)(Bb + (size_t)(row0 + (c)*8 + r8b) * ND + c8b*8) = pk_.u;    \
    } while (0)

    // stage decomposition (source col-slot pre-swizzled; reader same XOR)
    #define STAGE1(k0, dA, dT) do {                                          \
        { int r_ = tid >> 2, sl_ = tid & 3, cs_ = sl_ ^ ((r_ >> 1) & 3);     \
          GLDS(Ab + (size_t)(row0 + r_) * ND + (k0) + cs_ * 8, (dA) + tid * 8); } \
        _Pragma("unroll")                                                    \
        for (int i_ = 0; i_ < 4; ++i_) {                                     \
            int s_ = i_ * 512 + tid, r_ = s_ >> 2, sl_ = s_ & 3;             \
            int cs_ = sl_ ^ ((r_ >> 1) & 3);                                 \
            GLDS(attT + (size_t)r_ * ND + (k0) + cs_ * 8, (dT) + s_ * 8); }  \
    } while (0)
    #define STAGE2(k0, dB, dC) do {                                          \
        int r_ = tid >> 2, sl_ = tid & 3, cs_ = sl_ ^ ((r_ >> 1) & 3);       \
        GLDS(Bb + (size_t)(row0 + r_) * ND + (k0) + cs_ * 8, (dB) + tid * 8);\
        GLDS(Ab + (size_t)(row0 + r_) * ND + (k0) + cs_ * 8, (dC) + tid * 8);\
    } while (0)

    // ---------------- Phase 1: T = A @ attT^T (BK=32, dbuf) ----------------
    f32x4 acc1[4][8] = {};
    STAGE1(0, stA0, stT0);                    // step-0 stage in flight
    BG_ISSUE(0); BG_ISSUE(1);                 // B-gather 2 chunks in flight

    #pragma unroll
    for (int t = 0; t < 16; ++t) {
        BG_COMMIT(t);                         // chunk t: convert+sumsq+store
        if (t < 15) {
            STAGE1((t + 1) * 32, (t & 1) ? stA0 : stA1, (t & 1) ? stT0 : stT1);
            // outstanding newer than stage(t): chunk(t+1) 2 + store 1 + stage(t+1) 5
            asm volatile("s_waitcnt vmcnt(8)" ::: "memory");
        } else {
            asm volatile("s_waitcnt vmcnt(1)" ::: "memory");   // store only
        }
        __builtin_amdgcn_s_barrier();
        const bf16* A_ = (t & 1) ? stA1 : stA0;
        const bf16* T_ = (t & 1) ? stT1 : stT0;
        bf16x8 af[4], bfm[8];
        #pragma unroll
        for (int t4 = 0; t4 < 4; ++t4) {
            int R = wm + t4 * 16 + lm;
            af[t4] = *(const bf16x8*)&A_[R * 32 + (quad ^ ((R >> 1) & 3)) * 8];
        }
        #pragma unroll
        for (int t8 = 0; t8 < 8; ++t8) {
            int R = wn1 + t8 * 16 + lm;
            bfm[t8] = *(const bf16x8*)&T_[R * 32 + (quad ^ ((R >> 1) & 3)) * 8];
        }
        __builtin_amdgcn_s_setprio(1);
        #pragma unroll
        for (int im = 0; im < 4; ++im)
            #pragma unroll
            for (int jn = 0; jn < 8; ++jn)
                acc1[im][jn] = __builtin_amdgcn_mfma_f32_16x16x32_bf16(
                    af[im], bfm[jn], acc1[im][jn], 0, 0, 0);
        __builtin_amdgcn_s_setprio(0);
        if (t < 14) BG_ISSUE(t + 2);          // loads fly under next 2 steps
        __builtin_amdgcn_s_barrier();
    }

    // ---- ssB block reduce (redB area free until Tls epilogue) ----
    for (int o = 32; o; o >>= 1) pb += __shfl_xor(pb, o);
    if (lane == 0) redB[w] = pb;
    __syncthreads();
    float ssB = redB[0] + redB[1] + redB[2] + redB[3]
              + redB[4] + redB[5] + redB[6] + redB[7];
    __syncthreads();

    // Phase-1 epilogue: acc1 -> bf16 swizzled Tls (stage bufs dead).
    #pragma unroll
    for (int im = 0; im < 4; ++im)
    #pragma unroll
    for (int jn = 0; jn < 8; ++jn)
    #pragma unroll
    for (int p = 0; p < 4; ++p) {
        int m = wm + im * 16 + quad * 4 + p;   // C/D: col=lane&15, row=quad*4+reg
        int n = wn1 + jn * 16 + lm;
        int ks = n >> 5, kq = (n >> 3) & 3, e = n & 7;
        int pos = kq ^ ((m >> 2) & 3);
        Tls[ks * 4096 + m * 32 + pos * 8 + e] = (bf16)acc1[im][jn][p];
    }
    __syncthreads();                          // drains B stores too (vmcnt 0)

    // ------- Phase 2: S = T @ B^T  and  G = A @ diag(w) @ B^T -------
    f32x4 acc2[4][2] = {}, accG[4][2] = {};
    STAGE2(0, sB0, sC0);                      // safe: B stores drained above

    #pragma unroll
    for (int t = 0; t < 16; ++t) {
        if (t < 15) {
            STAGE2((t + 1) * 32, (t & 1) ? sB0 : sB1, (t & 1) ? sC0 : sC1);
            asm volatile("s_waitcnt vmcnt(2)" ::: "memory");
        } else {
            asm volatile("s_waitcnt vmcnt(0)" ::: "memory");
        }
        __builtin_amdgcn_s_barrier();
        const bf16* B_ = (t & 1) ? sB1 : sB0;
        const bf16* C_ = (t & 1) ? sC1 : sC0;
        float4 w0 = *(const float4*)(w_pred + t * 32 + quad * 8);
        float4 w1 = *(const float4*)(w_pred + t * 32 + quad * 8 + 4);
        float wv[8] = {w0.x, w0.y, w0.z, w0.w, w1.x, w1.y, w1.z, w1.w};
        bf16x8 af[4], af2[4], bf2[2], bfw[2];
        #pragma unroll
        for (int t4 = 0; t4 < 4; ++t4) {
            int R = wm + t4 * 16 + lm;
            af[t4]  = *(const bf16x8*)&Tls[t * 4096 + R * 32 + (quad ^ ((R >> 2) & 3)) * 8];
            af2[t4] = *(const bf16x8*)&C_[R * 32 + (quad ^ ((R >> 1) & 3)) * 8];
        }
        #pragma unroll
        for (int t2 = 0; t2 < 2; ++t2) {
            int R = wn2 + t2 * 16 + lm;
            bf2[t2] = *(const bf16x8*)&B_[R * 32 + (quad ^ ((R >> 1) & 3)) * 8];
            #pragma unroll
            for (int j = 0; j < 8; ++j)
                bfw[t2][j] = (bf16)((float)bf2[t2][j] * wv[j]);
        }
        __builtin_amdgcn_s_setprio(1);
        #pragma unroll
        for (int im = 0; im < 4; ++im)
            #pragma unroll
            for (int jn = 0; jn < 2; ++jn) {
                acc2[im][jn] = __builtin_amdgcn_mfma_f32_16x16x32_bf16(
                    af[im], bf2[jn], acc2[im][jn], 0, 0, 0);
                accG[im][jn] = __builtin_amdgcn_mfma_f32_16x16x32_bf16(
                    af2[im], bfw[jn], accG[im][jn], 0, 0, 0);
            }
        __builtin_amdgcn_s_setprio(0);
        __builtin_amdgcn_s_barrier();
    }

    // ---- S epilogue: tanh + store + row/col sums (Tls dead -> smalls) ----
    const float sc = rsqrtf(ssA * ssB);
    float* __restrict__ Sb = Sout + (size_t)b * NL * NL;
    #pragma unroll
    for (int im = 0; im < 4; ++im)
    #pragma unroll
    for (int jn = 0; jn < 2; ++jn)
    #pragma unroll
    for (int p = 0; p < 4; ++p) {
        float v = tanhf(acc2[im][jn][p] * sc);
        acc2[im][jn][p] = v;
        int m = wm + im * 16 + quad * 4 + p;
        int n = wn2 + jn * 16 + lm;
        __builtin_nontemporal_store(v, &Sb[m * NL + n]);
    }
    #pragma unroll
    for (int im = 0; im < 4; ++im)
    #pragma unroll
    for (int p = 0; p < 4; ++p) {
        float r = acc2[im][0][p] + acc2[im][1][p];
        r += __shfl_xor(r, 1); r += __shfl_xor(r, 2);
        r += __shfl_xor(r, 4); r += __shfl_xor(r, 8);
        if (lm == 0) rowb[(w >> 1) * NL + wm + im * 16 + quad * 4 + p] = r;
    }
    #pragma unroll
    for (int jn = 0; jn < 2; ++jn) {
        float cv = 0.f;
        #pragma unroll
        for (int im = 0; im < 4; ++im)
            #pragma unroll
            for (int p = 0; p < 4; ++p) cv += acc2[im][jn][p];
        cv += __shfl_xor(cv, 16); cv += __shfl_xor(cv, 32);
        if (quad == 0) colb[(w & 1) * NL + wn2 + jn * 16 + lm] = cv;
    }
    __syncthreads();

    // ---- softmax over means (wave0: rows, wave1: cols) ----
    if (tid < 64) {
        float a  = (rowb[tid] + rowb[NL + tid] + rowb[2 * NL + tid] + rowb[3 * NL + tid]) * (1.f / NL);
        float c2 = (rowb[tid + 64] + rowb[NL + tid + 64] + rowb[2 * NL + tid + 64] + rowb[3 * NL + tid + 64]) * (1.f / NL);
        float mx = fmaxf(a, c2);
        for (int o = 32; o; o >>= 1) mx = fmaxf(mx, __shfl_xor(mx, o));
        float e0 = expf(a - mx), e1 = expf(c2 - mx);
        float s = e0 + e1;
        for (int o = 32; o; o >>= 1) s += __shfl_xor(s, o);
        float inv = 1.f / s;
        wrow[tid] = e0 * inv; wrow[tid + 64] = e1 * inv;
    } else if (tid < 128) {
        int q = tid - 64;
        float a  = (colb[q] + colb[NL + q]) * (1.f / NL);
        float c2 = (colb[q + 64] + colb[NL + q + 64]) * (1.f / NL);
        float mx = fmaxf(a, c2);
        for (int o = 32; o; o >>= 1) mx = fmaxf(mx, __shfl_xor(mx, o));
        float e0 = expf(a - mx), e1 = expf(c2 - mx);
        float s = e0 + e1;
        for (int o = 32; o; o >>= 1) s += __shfl_xor(s, o);
        float inv = 1.f / s;
        wcol[q] = e0 * inv; wcol[q + 64] = e1 * inv;
    }
    __syncthreads();

    // ---- logit = sc * wrow^T G wcol ----
    float wc0 = wcol[wn2 + lm], wc1 = wcol[wn2 + 16 + lm];
    float g = 0.f;
    #pragma unroll
    for (int im = 0; im < 4; ++im)
    #pragma unroll
    for (int p = 0; p < 4; ++p) {
        float wr = wrow[wm + im * 16 + quad * 4 + p];
        g += wr * (wc0 * accG[im][0][p] + wc1 * accG[im][1][p]);
    }
    for (int o = 32; o; o >>= 1) g += __shfl_xor(g, o);
    if (lane == 0) red2[w] = g;
    __syncthreads();
    if (tid == 0) {
        float tot = 0.f;
        #pragma unroll
        for (int i = 0; i < 8; ++i) tot += red2[i];
        logits[b] = tot * sc + b_pred[0];
    }
}

extern "C" void kernel_launch(void* const* d_in, const int* in_sizes, int n_in,
                              void* d_out, int out_size, void* d_ws, size_t ws_size,
                              hipStream_t stream) {
    const int*   t1c = (const int*)d_in[2];
    const int*   t2c = (const int*)d_in[3];
    const float* emb = (const float*)d_in[4];
    const float* att = (const float*)d_in[5];
    const float* wp  = (const float*)d_in[6];
    const float* bp  = (const float*)d_in[7];

    float* out    = (float*)d_out;
    float* logits = out;
    float* S      = out + NB;      // outputs: logits(512) then S(512*128*128)

    char* ws = (char*)d_ws;
    bf16*  Ab   = (bf16*)(ws);                              // 67,108,864 B
    bf16*  Bb   = (bf16*)(ws + 67108864);                   // 67,108,864 B
    bf16*  attT = (bf16*)(ws + 134217728);                  //    524,288 B
    float* ss   = (float*)(ws + 134742016);                 //      4,096 B

    hipMemsetAsync(ss, 0, 4096, stream);
    // A-side gather (y=0) + att transpose (y=1); B-gather lives in k_mega2b
    k_gather<<<dim3(NB, 2, 8), 256, 0, stream>>>(t1c, emb, Ab, ss, att, attT);
    // compute: ph1 with embedded B-gather, ph2 S+G, softmax, logits
    k_mega2b<<<dim3(NB), 512, 0, stream>>>(Ab, attT, Bb, t2c, emb,
                                           S, ss, wp, bp, logits);
}